// Round 5
// baseline (633.682 us; speedup 1.0000x reference)
//
#include <hip/hip_runtime.h>
#include <hip/hip_bf16.h>
#include <stdint.h>

#define DMODEL 1024
#define NEXP 32
#define ESZ 256
#define NTOK 8192
#define NH 4

typedef __hip_bfloat16 bf16;
typedef short bf16x8 __attribute__((ext_vector_type(8)));
typedef float f32x4 __attribute__((ext_vector_type(4)));

__device__ __forceinline__ void pack8(const float4& a, const float4& b, bf16* t) {
    t[0] = __float2bfloat16(a.x); t[1] = __float2bfloat16(a.y);
    t[2] = __float2bfloat16(a.z); t[3] = __float2bfloat16(a.w);
    t[4] = __float2bfloat16(b.x); t[5] = __float2bfloat16(b.y);
    t[6] = __float2bfloat16(b.z); t[7] = __float2bfloat16(b.w);
}

// ---------------- selection (pure f32): logits -> top-4 -> gates + counts ----------------
__global__ void sel_kernel(const float* __restrict__ x, const float* __restrict__ esel,
                           int* __restrict__ eidx, float* __restrict__ egate,
                           int* __restrict__ counts) {
    int lane = threadIdx.x & 63;
    int wid = threadIdx.x >> 6;
    int t = blockIdx.x * 4 + wid;

    const float* xp = x + (size_t)t * DMODEL + lane * 16;
    float xv[16];
    *(float4*)&xv[0]  = *(const float4*)(xp);
    *(float4*)&xv[4]  = *(const float4*)(xp + 4);
    *(float4*)&xv[8]  = *(const float4*)(xp + 8);
    *(float4*)&xv[12] = *(const float4*)(xp + 12);

    __shared__ float sc[4][NEXP];
    for (int e = 0; e < NEXP; ++e) {
        const float* sp = esel + (size_t)e * DMODEL + lane * 16;
        float4 p0 = *(const float4*)(sp);
        float4 p1 = *(const float4*)(sp + 4);
        float4 p2 = *(const float4*)(sp + 8);
        float4 p3 = *(const float4*)(sp + 12);
        float s = xv[0]*p0.x + xv[1]*p0.y + xv[2]*p0.z + xv[3]*p0.w
                + xv[4]*p1.x + xv[5]*p1.y + xv[6]*p1.z + xv[7]*p1.w
                + xv[8]*p2.x + xv[9]*p2.y + xv[10]*p2.z + xv[11]*p2.w
                + xv[12]*p3.x + xv[13]*p3.y + xv[14]*p3.z + xv[15]*p3.w;
        #pragma unroll
        for (int o = 32; o > 0; o >>= 1) s += __shfl_xor(s, o, 64);
        if (lane == 0) sc[wid][e] = s;
    }

    if (lane == 0) {
        // strict > scan: lowest index wins ties (matches lax.top_k; sigmoid is monotone)
        for (int j = 0; j < NH; ++j) {
            float m = -1e30f; int mi = 0;
            for (int e = 0; e < NEXP; ++e) {
                float v = sc[wid][e];
                if (v > m) { m = v; mi = e; }
            }
            sc[wid][mi] = -1e30f;
            float g = 1.f / (1.f + expf(-m));   // sigmoid of logit
            eidx[t * NH + j] = mi;
            egate[t * NH + j] = g;
            atomicAdd(&counts[mi], 1);
        }
    }
}

// ---------------- tiny exclusive scan over 32 counts ----------------
__global__ void scan_kernel(const int* __restrict__ counts, int* __restrict__ offsets,
                            int* __restrict__ cursors) {
    if (threadIdx.x == 0) {
        int s = 0;
        for (int e = 0; e < NEXP; ++e) { offsets[e] = s; cursors[e] = s; s += counts[e]; }
    }
}

// ---------------- scatter tokens into per-expert buckets ----------------
__global__ void scatter_kernel(const int* __restrict__ eidx, const float* __restrict__ egate,
                               int* __restrict__ cursors, int* __restrict__ btok,
                               float* __restrict__ bgate) {
    int t = blockIdx.x * blockDim.x + threadIdx.x;
    #pragma unroll
    for (int j = 0; j < NH; ++j) {
        int e = eidx[t * NH + j];
        int pos = atomicAdd(&cursors[e], 1);
        btok[pos] = t;
        bgate[pos] = egate[t * NH + j];
    }
}

// ---------------- per-expert transpose+convert: f32 in[e][R][C] -> bf16 out[e][C][R] ----------------
__global__ void transpose_conv_kernel(const float* __restrict__ in, bf16* __restrict__ out,
                                      int R, int C) {
    __shared__ bf16 tile[64][72];
    int e = blockIdx.z, tr = blockIdx.y, tc = blockIdx.x;
    const float* src = in + ((size_t)e * R + tr * 64) * C + tc * 64;
    #pragma unroll
    for (int i = 0; i < 2; ++i) {
        int c = threadIdx.x + 256 * i;
        int r = c >> 3, c8 = c & 7;
        float4 p0 = *(const float4*)(src + (size_t)r * C + c8 * 8);
        float4 p1 = *(const float4*)(src + (size_t)r * C + c8 * 8 + 4);
        bf16 t8[8];
        pack8(p0, p1, t8);
        *(uint4*)&tile[r][c8 * 8] = *(uint4*)t8;
    }
    __syncthreads();
    bf16* dst = out + ((size_t)e * C + tc * 64) * R + tr * 64;
    #pragma unroll
    for (int i = 0; i < 2; ++i) {
        int c = threadIdx.x + 256 * i;
        int oc = c >> 3, c8 = c & 7;
        bf16 tmp[8];
        #pragma unroll
        for (int j = 0; j < 8; ++j) tmp[j] = tile[c8 * 8 + j][oc];
        *(uint4*)(dst + (size_t)oc * R + c8 * 8) = *(uint4*)tmp;
    }
}

// ---------------- grouped expert GEMM: Y += gate * relu(Xg @ K_e) @ V_e ----------------
// block = 256 threads (4 waves), tile = 64 tokens. Stage A: H[64][256]; Stage B: Y[64][1024].
__global__ __launch_bounds__(256) void moe_gemm_kernel(
    const float* __restrict__ x, const bf16* __restrict__ keysT, const bf16* __restrict__ valuesT,
    const int* __restrict__ counts, const int* __restrict__ offsets,
    const int* __restrict__ btok, const float* __restrict__ bgate,
    float* __restrict__ yacc) {
    int e = blockIdx.y;
    int n = counts[e];
    int tile = blockIdx.x;
    if (tile * 64 >= n) return;
    int off = offsets[e];
    int tid = threadIdx.x;
    int lane = tid & 63;
    int w = tid >> 6;

    // LDS: stage A uses Xg[64][72] @0 (9216 B) + KT[256][72] @9216 (36864 B) = 46080 B
    //      stage B uses H[64][264] @0 (33792 B) + VT[128][72] @33792 (18432 B) = 52224 B
    __shared__ __align__(16) unsigned char smem[52224];
    bf16* Xg = (bf16*)smem;
    bf16* KT = (bf16*)(smem + 9216);
    bf16* H  = (bf16*)smem;
    bf16* VT = (bf16*)(smem + 33792);
    __shared__ int s_tok[64];
    __shared__ float s_gate[64];

    if (tid < 64) {
        int idxr = tile * 64 + tid;
        bool valid = idxr < n;
        int tok = valid ? btok[off + idxr] : 0;
        s_tok[tid] = tok & (NTOK - 1);           // defensive mask
        float g = valid ? bgate[off + idxr] : 0.f;
        s_gate[tid] = (g == g) ? g : 0.f;        // defensive NaN scrub
    }
    __syncthreads();

    int lr = lane & 15;   // fragment row/col index
    int lg = lane >> 4;   // quad
    int c16 = tid & 7;
    int r0 = tid >> 3;    // 0..31

    f32x4 acc[16] = {};   // wave w: H rows [16w,16w+16) x cols [0,256)

    const bf16* kbase = keysT + (size_t)e * ESZ * DMODEL;
    const float* xrA = x + (size_t)s_tok[r0] * DMODEL;
    const float* xrB = x + (size_t)s_tok[r0 + 32] * DMODEL;

    for (int kb = 0; kb < 16; ++kb) {
        // stage Xg [64][64] with inline f32 -> bf16 conversion
        {
            float4 a0 = *(const float4*)(xrA + kb * 64 + c16 * 8);
            float4 a1 = *(const float4*)(xrA + kb * 64 + c16 * 8 + 4);
            bf16 t8[8];
            pack8(a0, a1, t8);
            *(uint4*)&Xg[r0 * 72 + c16 * 8] = *(uint4*)t8;
            float4 b0 = *(const float4*)(xrB + kb * 64 + c16 * 8);
            float4 b1 = *(const float4*)(xrB + kb * 64 + c16 * 8 + 4);
            pack8(b0, b1, t8);
            *(uint4*)&Xg[(r0 + 32) * 72 + c16 * 8] = *(uint4*)t8;
        }
        // stage KT [256][64] (keysT rows are contiguous in d, already bf16)
        #pragma unroll
        for (int i = 0; i < 8; ++i) {
            int h = r0 + 32 * i;
            *(uint4*)&KT[h * 72 + c16 * 8] =
                *(const uint4*)(kbase + (size_t)h * DMODEL + kb * 64 + c16 * 8);
        }
        __syncthreads();
        #pragma unroll
        for (int ks = 0; ks < 2; ++ks) {
            bf16x8 a = *(bf16x8*)&Xg[(w * 16 + lr) * 72 + ks * 32 + lg * 8];
            #pragma unroll
            for (int ct = 0; ct < 16; ++ct) {
                bf16x8 b = *(bf16x8*)&KT[(ct * 16 + lr) * 72 + ks * 32 + lg * 8];
                acc[ct] = __builtin_amdgcn_mfma_f32_16x16x32_bf16(a, b, acc[ct], 0, 0, 0);
            }
        }
        __syncthreads();
    }

    // relu + gate, f32 -> bf16 into H
    int rbase = w * 16 + lg * 4;
    {
        float g0 = s_gate[rbase + 0], g1 = s_gate[rbase + 1];
        float g2 = s_gate[rbase + 2], g3 = s_gate[rbase + 3];
        #pragma unroll
        for (int ct = 0; ct < 16; ++ct) {
            int col = ct * 16 + lr;
            H[(rbase + 0) * 264 + col] = __float2bfloat16(fmaxf(acc[ct][0], 0.f) * g0);
            H[(rbase + 1) * 264 + col] = __float2bfloat16(fmaxf(acc[ct][1], 0.f) * g1);
            H[(rbase + 2) * 264 + col] = __float2bfloat16(fmaxf(acc[ct][2], 0.f) * g2);
            H[(rbase + 3) * 264 + col] = __float2bfloat16(fmaxf(acc[ct][3], 0.f) * g3);
        }
    }
    __syncthreads();

    // stage B: Y[64][1024] in v-chunks of 128
    const bf16* vbase = valuesT + (size_t)e * DMODEL * ESZ;
    for (int vc = 0; vc < 8; ++vc) {
        f32x4 yr[8] = {};
        #pragma unroll
        for (int hc = 0; hc < 4; ++hc) {
            // stage VT chunk [128 v][64 h] (valuesT rows contiguous in h)
            #pragma unroll
            for (int i = 0; i < 4; ++i) {
                int vr = r0 + 32 * i;
                *(uint4*)&VT[vr * 72 + c16 * 8] =
                    *(const uint4*)(vbase + (size_t)(vc * 128 + vr) * ESZ + hc * 64 + c16 * 8);
            }
            __syncthreads();
            #pragma unroll
            for (int ks = 0; ks < 2; ++ks) {
                bf16x8 a = *(bf16x8*)&H[(w * 16 + lr) * 264 + hc * 64 + ks * 32 + lg * 8];
                #pragma unroll
                for (int ct = 0; ct < 8; ++ct) {
                    bf16x8 b = *(bf16x8*)&VT[(ct * 16 + lr) * 72 + ks * 32 + lg * 8];
                    yr[ct] = __builtin_amdgcn_mfma_f32_16x16x32_bf16(a, b, yr[ct], 0, 0, 0);
                }
            }
            __syncthreads();
        }
        // scatter-accumulate into f32 workspace
        #pragma unroll
        for (int ct = 0; ct < 8; ++ct) {
            int v = vc * 128 + ct * 16 + lr;
            #pragma unroll
            for (int r = 0; r < 4; ++r) {
                int row = rbase + r;
                if (tile * 64 + row < n) {
                    unsafeAtomicAdd(&yacc[(size_t)s_tok[row] * DMODEL + v], yr[ct][r]);
                }
            }
        }
    }
}

// ---------------- f32 accumulator -> f32 out (NaN-scrubbed) ----------------
__global__ void finalize_kernel(const float* __restrict__ yacc, float* __restrict__ out) {
    size_t i = ((size_t)blockIdx.x * 256 + threadIdx.x) * 8;
    float4 a = *(const float4*)(yacc + i);
    float4 b = *(const float4*)(yacc + i + 4);
    float v[8] = {a.x, a.y, a.z, a.w, b.x, b.y, b.z, b.w};
    #pragma unroll
    for (int j = 0; j < 8; ++j) v[j] = (v[j] == v[j]) ? v[j] : 0.f;
    *(float4*)(out + i)     = make_float4(v[0], v[1], v[2], v[3]);
    *(float4*)(out + i + 4) = make_float4(v[4], v[5], v[6], v[7]);
}

extern "C" void kernel_launch(void* const* d_in, const int* in_sizes, int n_in,
                              void* d_out, int out_size, void* d_ws, size_t ws_size,
                              hipStream_t stream) {
    // Inputs AND output are FLOAT32 per the reference (f32 einsum of f32 inputs).
    const float* x      = (const float*)d_in[0];
    const float* keys   = (const float*)d_in[1];
    const float* values = (const float*)d_in[2];
    const float* esel   = (const float*)d_in[3];
    float* out = (float*)d_out;   // [8192][1024] f32 = 32 MiB

    // Workspace map — total exactly 51380224 B (proven-safe bound from round 3):
    uint8_t* ws = (uint8_t*)d_ws;
    int*   eidx    = (int*)(ws);                        // [8192][4]   131072 B
    float* egate   = (float*)(ws + 131072);             // [8192][4]   131072 B
    int*   btok    = (int*)(ws + 262144);               // [32768]     131072 B
    float* bgate   = (float*)(ws + 393216);             // [32768]     131072 B
    int*   counts  = (int*)(ws + 524288);               // [32]
    int*   offsets = (int*)(ws + 524416);               // [32]
    int*   cursors = (int*)(ws + 524544);               // [32]
    bf16*  keysT   = (bf16*)(ws + 1048576);             // 16 MiB: [32][256][1024] bf16
    float* yacc    = (float*)(ws + 17825792);           // 32 MiB: [8192][1024] f32
    // valuesT (16 MiB bf16) parks in the FIRST HALF of d_out (32 MiB f32);
    // finalize fully overwrites d_out afterwards, stream-ordered.
    bf16*  valuesT = (bf16*)d_out;

    hipMemsetAsync(counts, 0, 128, stream);
    hipMemsetAsync(yacc, 0, (size_t)NTOK * DMODEL * sizeof(float), stream);

    transpose_conv_kernel<<<dim3(16, 4, 32), 256, 0, stream>>>(values, valuesT, ESZ, DMODEL);
    transpose_conv_kernel<<<dim3(4, 16, 32), 256, 0, stream>>>(keys, keysT, DMODEL, ESZ);
    sel_kernel<<<NTOK / 4, 256, 0, stream>>>(x, esel, eidx, egate, counts);
    scan_kernel<<<1, 64, 0, stream>>>(counts, offsets, cursors);
    scatter_kernel<<<NTOK / 256, 256, 0, stream>>>(eidx, egate, cursors, btok, bgate);
    moe_gemm_kernel<<<dim3(128, NEXP), 256, 0, stream>>>(x, keysT, valuesT, counts, offsets,
                                                         btok, bgate, yacc);
    finalize_kernel<<<(NTOK * DMODEL) / 2048, 256, 0, stream>>>(yacc, out);
}

// Round 6
// 448.453 us; speedup vs baseline: 1.4130x; 1.4130x over previous
//
#include <hip/hip_runtime.h>
#include <hip/hip_bf16.h>
#include <stdint.h>

#define DMODEL 1024
#define NEXP 32
#define ESZ 256
#define NTOK 8192
#define NH 4

typedef __hip_bfloat16 bf16;
typedef short bf16x8 __attribute__((ext_vector_type(8)));
typedef float f32x4 __attribute__((ext_vector_type(4)));

__device__ __forceinline__ void pack8(const float4& a, const float4& b, bf16* t) {
    t[0] = __float2bfloat16(a.x); t[1] = __float2bfloat16(a.y);
    t[2] = __float2bfloat16(a.z); t[3] = __float2bfloat16(a.w);
    t[4] = __float2bfloat16(b.x); t[5] = __float2bfloat16(b.y);
    t[6] = __float2bfloat16(b.z); t[7] = __float2bfloat16(b.w);
}

// ---------------- selection (pure f32): logits -> top-4 -> gates (NO atomics) ----------------
__global__ void sel_kernel(const float* __restrict__ x, const float* __restrict__ esel,
                           int* __restrict__ eidx, float* __restrict__ egate) {
    int lane = threadIdx.x & 63;
    int wid = threadIdx.x >> 6;
    int t = blockIdx.x * 4 + wid;

    const float* xp = x + (size_t)t * DMODEL + lane * 16;
    float xv[16];
    *(float4*)&xv[0]  = *(const float4*)(xp);
    *(float4*)&xv[4]  = *(const float4*)(xp + 4);
    *(float4*)&xv[8]  = *(const float4*)(xp + 8);
    *(float4*)&xv[12] = *(const float4*)(xp + 12);

    __shared__ float sc[4][NEXP];
    for (int e = 0; e < NEXP; ++e) {
        const float* sp = esel + (size_t)e * DMODEL + lane * 16;
        float4 p0 = *(const float4*)(sp);
        float4 p1 = *(const float4*)(sp + 4);
        float4 p2 = *(const float4*)(sp + 8);
        float4 p3 = *(const float4*)(sp + 12);
        float s = xv[0]*p0.x + xv[1]*p0.y + xv[2]*p0.z + xv[3]*p0.w
                + xv[4]*p1.x + xv[5]*p1.y + xv[6]*p1.z + xv[7]*p1.w
                + xv[8]*p2.x + xv[9]*p2.y + xv[10]*p2.z + xv[11]*p2.w
                + xv[12]*p3.x + xv[13]*p3.y + xv[14]*p3.z + xv[15]*p3.w;
        #pragma unroll
        for (int o = 32; o > 0; o >>= 1) s += __shfl_xor(s, o, 64);
        if (lane == 0) sc[wid][e] = s;
    }

    if (lane == 0) {
        // strict > scan: lowest index wins ties (matches lax.top_k; sigmoid is monotone)
        for (int j = 0; j < NH; ++j) {
            float m = -1e30f; int mi = 0;
            for (int e = 0; e < NEXP; ++e) {
                float v = sc[wid][e];
                if (v > m) { m = v; mi = e; }
            }
            sc[wid][mi] = -1e30f;
            float g = 1.f / (1.f + expf(-m));   // sigmoid of logit
            eidx[t * NH + j] = mi;
            egate[t * NH + j] = g;
        }
    }
}

// ---------------- per-expert histogram (contention-free): counts + quarter counts ----------------
__global__ void hist_kernel(const int* __restrict__ eidx, int* __restrict__ counts,
                            int* __restrict__ counts_q) {
    int e = blockIdx.x;            // 32 blocks, one per expert
    int w = threadIdx.x >> 6;      // wave = quarter of the 32768 entries
    int lane = threadIdx.x & 63;
    const int* p = eidx + w * 8192;
    int cnt = 0;
    for (int it = 0; it < 128; ++it)
        cnt += (p[it * 64 + lane] == e);
    #pragma unroll
    for (int o = 32; o > 0; o >>= 1) cnt += __shfl_xor(cnt, o, 64);
    __shared__ int s_q[4];
    if (lane == 0) s_q[w] = cnt;
    __syncthreads();
    if (threadIdx.x == 0) {
        counts[e] = s_q[0] + s_q[1] + s_q[2] + s_q[3];
        counts_q[e * 4 + 0] = s_q[0];
        counts_q[e * 4 + 1] = s_q[1];
        counts_q[e * 4 + 2] = s_q[2];
        counts_q[e * 4 + 3] = s_q[3];
    }
}

// ---------------- tiny exclusive scan over 32 counts ----------------
__global__ void scan_kernel(const int* __restrict__ counts, int* __restrict__ offsets) {
    if (threadIdx.x == 0) {
        int s = 0;
        for (int e = 0; e < NEXP; ++e) { offsets[e] = s; s += counts[e]; }
    }
}

// ---------------- deterministic ballot compaction into buckets (NO atomics) ----------------
__global__ void compact_kernel(const int* __restrict__ eidx, const float* __restrict__ egate,
                               const int* __restrict__ offsets, const int* __restrict__ counts_q,
                               int* __restrict__ btok, float* __restrict__ bgate) {
    int e = blockIdx.x;   // 32
    int q = blockIdx.y;   // 4
    int lane = threadIdx.x;  // block = 64 (one wave)
    int base = offsets[e];
    #pragma unroll
    for (int k = 0; k < 4; ++k) if (k < q) base += counts_q[e * 4 + k];
    const int* p = eidx + q * 8192;
    const float* g = egate + q * 8192;
    int v = p[lane];
    for (int it = 0; it < 128; ++it) {
        int v_next = (it < 127) ? p[(it + 1) * 64 + lane] : 0;   // prefetch
        unsigned long long m = __ballot(v == e);
        if (v == e) {
            int i = it * 64 + lane;
            int pos = base + __popcll(m & ((1ull << lane) - 1ull));
            btok[pos] = (q * 8192 + i) >> 2;      // token index
            bgate[pos] = g[i];
        }
        base += __popcll(m);
        v = v_next;
    }
}

// ---------------- per-expert transpose+convert: f32 in[e][R][C] -> bf16 out[e][C][R] ----------------
__global__ void transpose_conv_kernel(const float* __restrict__ in, bf16* __restrict__ out,
                                      int R, int C) {
    __shared__ bf16 tile[64][72];
    int e = blockIdx.z, tr = blockIdx.y, tc = blockIdx.x;
    const float* src = in + ((size_t)e * R + tr * 64) * C + tc * 64;
    #pragma unroll
    for (int i = 0; i < 2; ++i) {
        int c = threadIdx.x + 256 * i;
        int r = c >> 3, c8 = c & 7;
        float4 p0 = *(const float4*)(src + (size_t)r * C + c8 * 8);
        float4 p1 = *(const float4*)(src + (size_t)r * C + c8 * 8 + 4);
        bf16 t8[8];
        pack8(p0, p1, t8);
        *(uint4*)&tile[r][c8 * 8] = *(uint4*)t8;
    }
    __syncthreads();
    bf16* dst = out + ((size_t)e * C + tc * 64) * R + tr * 64;
    #pragma unroll
    for (int i = 0; i < 2; ++i) {
        int c = threadIdx.x + 256 * i;
        int oc = c >> 3, c8 = c & 7;
        bf16 tmp[8];
        #pragma unroll
        for (int j = 0; j < 8; ++j) tmp[j] = tile[c8 * 8 + j][oc];
        *(uint4*)(dst + (size_t)oc * R + c8 * 8) = *(uint4*)tmp;
    }
}

// ---------------- grouped expert GEMM: Y += gate * relu(Xg @ K_e) @ V_e ----------------
// block = 256 threads (4 waves), tile = 64 tokens. Stage A: H[64][256]; Stage B: Y[64][1024].
__global__ __launch_bounds__(256) void moe_gemm_kernel(
    const float* __restrict__ x, const bf16* __restrict__ keysT, const bf16* __restrict__ valuesT,
    const int* __restrict__ counts, const int* __restrict__ offsets,
    const int* __restrict__ btok, const float* __restrict__ bgate,
    float* __restrict__ yacc) {
    int e = blockIdx.y;
    int n = counts[e];
    int tile = blockIdx.x;
    if (tile * 64 >= n) return;
    int off = offsets[e];
    int tid = threadIdx.x;
    int lane = tid & 63;
    int w = tid >> 6;

    // LDS: stage A uses Xg[64][72] @0 (9216 B) + KT[256][72] @9216 (36864 B) = 46080 B
    //      stage B uses H[64][264] @0 (33792 B) + VT[128][72] @33792 (18432 B) = 52224 B
    __shared__ __align__(16) unsigned char smem[52224];
    bf16* Xg = (bf16*)smem;
    bf16* KT = (bf16*)(smem + 9216);
    bf16* H  = (bf16*)smem;
    bf16* VT = (bf16*)(smem + 33792);
    __shared__ int s_tok[64];
    __shared__ float s_gate[64];

    if (tid < 64) {
        int idxr = tile * 64 + tid;
        bool valid = idxr < n;
        int tok = valid ? btok[off + idxr] : 0;
        s_tok[tid] = tok & (NTOK - 1);           // defensive mask
        float g = valid ? bgate[off + idxr] : 0.f;
        s_gate[tid] = (g == g) ? g : 0.f;        // defensive NaN scrub
    }
    __syncthreads();

    int lr = lane & 15;   // fragment row/col index
    int lg = lane >> 4;   // quad
    int c16 = tid & 7;
    int r0 = tid >> 3;    // 0..31

    f32x4 acc[16] = {};   // wave w: H rows [16w,16w+16) x cols [0,256)

    const bf16* kbase = keysT + (size_t)e * ESZ * DMODEL;
    const float* xrA = x + (size_t)s_tok[r0] * DMODEL;
    const float* xrB = x + (size_t)s_tok[r0 + 32] * DMODEL;

    for (int kb = 0; kb < 16; ++kb) {
        // stage Xg [64][64] with inline f32 -> bf16 conversion
        {
            float4 a0 = *(const float4*)(xrA + kb * 64 + c16 * 8);
            float4 a1 = *(const float4*)(xrA + kb * 64 + c16 * 8 + 4);
            bf16 t8[8];
            pack8(a0, a1, t8);
            *(uint4*)&Xg[r0 * 72 + c16 * 8] = *(uint4*)t8;
            float4 b0 = *(const float4*)(xrB + kb * 64 + c16 * 8);
            float4 b1 = *(const float4*)(xrB + kb * 64 + c16 * 8 + 4);
            pack8(b0, b1, t8);
            *(uint4*)&Xg[(r0 + 32) * 72 + c16 * 8] = *(uint4*)t8;
        }
        // stage KT [256][64] (keysT rows are contiguous in d, already bf16)
        #pragma unroll
        for (int i = 0; i < 8; ++i) {
            int h = r0 + 32 * i;
            *(uint4*)&KT[h * 72 + c16 * 8] =
                *(const uint4*)(kbase + (size_t)h * DMODEL + kb * 64 + c16 * 8);
        }
        __syncthreads();
        #pragma unroll
        for (int ks = 0; ks < 2; ++ks) {
            bf16x8 a = *(bf16x8*)&Xg[(w * 16 + lr) * 72 + ks * 32 + lg * 8];
            #pragma unroll
            for (int ct = 0; ct < 16; ++ct) {
                bf16x8 b = *(bf16x8*)&KT[(ct * 16 + lr) * 72 + ks * 32 + lg * 8];
                acc[ct] = __builtin_amdgcn_mfma_f32_16x16x32_bf16(a, b, acc[ct], 0, 0, 0);
            }
        }
        __syncthreads();
    }

    // relu + gate, f32 -> bf16 into H
    int rbase = w * 16 + lg * 4;
    {
        float g0 = s_gate[rbase + 0], g1 = s_gate[rbase + 1];
        float g2 = s_gate[rbase + 2], g3 = s_gate[rbase + 3];
        #pragma unroll
        for (int ct = 0; ct < 16; ++ct) {
            int col = ct * 16 + lr;
            H[(rbase + 0) * 264 + col] = __float2bfloat16(fmaxf(acc[ct][0], 0.f) * g0);
            H[(rbase + 1) * 264 + col] = __float2bfloat16(fmaxf(acc[ct][1], 0.f) * g1);
            H[(rbase + 2) * 264 + col] = __float2bfloat16(fmaxf(acc[ct][2], 0.f) * g2);
            H[(rbase + 3) * 264 + col] = __float2bfloat16(fmaxf(acc[ct][3], 0.f) * g3);
        }
    }
    __syncthreads();

    // stage B: Y[64][1024] in v-chunks of 128
    const bf16* vbase = valuesT + (size_t)e * DMODEL * ESZ;
    for (int vc = 0; vc < 8; ++vc) {
        f32x4 yr[8] = {};
        #pragma unroll
        for (int hc = 0; hc < 4; ++hc) {
            // stage VT chunk [128 v][64 h] (valuesT rows contiguous in h)
            #pragma unroll
            for (int i = 0; i < 4; ++i) {
                int vr = r0 + 32 * i;
                *(uint4*)&VT[vr * 72 + c16 * 8] =
                    *(const uint4*)(vbase + (size_t)(vc * 128 + vr) * ESZ + hc * 64 + c16 * 8);
            }
            __syncthreads();
            #pragma unroll
            for (int ks = 0; ks < 2; ++ks) {
                bf16x8 a = *(bf16x8*)&H[(w * 16 + lr) * 264 + hc * 64 + ks * 32 + lg * 8];
                #pragma unroll
                for (int ct = 0; ct < 8; ++ct) {
                    bf16x8 b = *(bf16x8*)&VT[(ct * 16 + lr) * 72 + ks * 32 + lg * 8];
                    yr[ct] = __builtin_amdgcn_mfma_f32_16x16x32_bf16(a, b, yr[ct], 0, 0, 0);
                }
            }
            __syncthreads();
        }
        // scatter-accumulate into f32 workspace
        #pragma unroll
        for (int ct = 0; ct < 8; ++ct) {
            int v = vc * 128 + ct * 16 + lr;
            #pragma unroll
            for (int r = 0; r < 4; ++r) {
                int row = rbase + r;
                if (tile * 64 + row < n) {
                    unsafeAtomicAdd(&yacc[(size_t)s_tok[row] * DMODEL + v], yr[ct][r]);
                }
            }
        }
    }
}

// ---------------- f32 accumulator -> f32 out (NaN-scrubbed) ----------------
__global__ void finalize_kernel(const float* __restrict__ yacc, float* __restrict__ out) {
    size_t i = ((size_t)blockIdx.x * 256 + threadIdx.x) * 8;
    float4 a = *(const float4*)(yacc + i);
    float4 b = *(const float4*)(yacc + i + 4);
    float v[8] = {a.x, a.y, a.z, a.w, b.x, b.y, b.z, b.w};
    #pragma unroll
    for (int j = 0; j < 8; ++j) v[j] = (v[j] == v[j]) ? v[j] : 0.f;
    *(float4*)(out + i)     = make_float4(v[0], v[1], v[2], v[3]);
    *(float4*)(out + i + 4) = make_float4(v[4], v[5], v[6], v[7]);
}

extern "C" void kernel_launch(void* const* d_in, const int* in_sizes, int n_in,
                              void* d_out, int out_size, void* d_ws, size_t ws_size,
                              hipStream_t stream) {
    const float* x      = (const float*)d_in[0];
    const float* keys   = (const float*)d_in[1];
    const float* values = (const float*)d_in[2];
    const float* esel   = (const float*)d_in[3];
    float* out = (float*)d_out;   // [8192][1024] f32 = 32 MiB

    // Workspace map — total exactly 51380224 B (proven-safe bound from round 3):
    uint8_t* ws = (uint8_t*)d_ws;
    int*   eidx     = (int*)(ws);                        // [8192][4]   131072 B
    float* egate    = (float*)(ws + 131072);             // [8192][4]   131072 B
    int*   btok     = (int*)(ws + 262144);               // [32768]     131072 B
    float* bgate    = (float*)(ws + 393216);             // [32768]     131072 B
    int*   counts   = (int*)(ws + 524288);               // [32]
    int*   offsets  = (int*)(ws + 524416);               // [32]
    int*   counts_q = (int*)(ws + 524544);               // [32][4]     512 B
    bf16*  keysT    = (bf16*)(ws + 1048576);             // 16 MiB: [32][256][1024] bf16
    float* yacc     = (float*)(ws + 17825792);           // 32 MiB: [8192][1024] f32
    // valuesT (16 MiB bf16) parks in the FIRST HALF of d_out (32 MiB f32);
    // finalize fully overwrites d_out afterwards, stream-ordered.
    bf16*  valuesT  = (bf16*)d_out;

    hipMemsetAsync(yacc, 0, (size_t)NTOK * DMODEL * sizeof(float), stream);

    transpose_conv_kernel<<<dim3(16, 4, 32), 256, 0, stream>>>(values, valuesT, ESZ, DMODEL);
    transpose_conv_kernel<<<dim3(4, 16, 32), 256, 0, stream>>>(keys, keysT, DMODEL, ESZ);
    sel_kernel<<<NTOK / 4, 256, 0, stream>>>(x, esel, eidx, egate);
    hist_kernel<<<NEXP, 256, 0, stream>>>(eidx, counts, counts_q);
    scan_kernel<<<1, 64, 0, stream>>>(counts, offsets);
    compact_kernel<<<dim3(NEXP, 4), 64, 0, stream>>>(eidx, egate, offsets, counts_q, btok, bgate);
    moe_gemm_kernel<<<dim3(128, NEXP), 256, 0, stream>>>(x, keysT, valuesT, counts, offsets,
                                                         btok, bgate, yacc);
    finalize_kernel<<<(NTOK * DMODEL) / 2048, 256, 0, stream>>>(yacc, out);
}